// Round 3
// baseline (698.123 us; speedup 1.0000x reference)
//
#include <hip/hip_runtime.h>
#include <hip/hip_bf16.h>
#include <math.h>

// AudioAttentionPooler on MI355X.
// B=32 T=2048 HIDDEN=1024 NH=16 HD=64 PROJ=1024.
//
// Algebra: K-projection folded into a [16][1024] matrix wqk (K-bias cancels in
// softmax); V-projection deferred until after pooling hidden (attn sums to 1,
// so V-bias adds directly). Two 256MiB streaming passes over hidden_states.
//
// ws layout (floats) — ~6.5 MB total (kept small; ws_size is opaque):
//   wqk     [16][1024]      @ 0        (16384)
//   logits  [32][16][2048]  @ 16384    (1048576)  (overwritten with softmax w)
//   pooled  [32][16][1024]  @ 1064960  (524288)   (atomicAdd accumulated)
//   out_pre [32][1024]      @ 1589248  (32768)

#define NH 16

// ---- kernel A: wqk[h][c] = scale * sum_d q[h*64+d] * kv_w[c][h*64+d] ----
__global__ __launch_bounds__(256) void k_wqk(const float* __restrict__ q,
                                             const float* __restrict__ kvw,
                                             float* __restrict__ wqk) {
  int t = blockIdx.x * 256 + threadIdx.x;  // 16384 = 1024 c * 16 h
  int c = t >> 4, h = t & 15;
  const float4* kvw4 = (const float4*)kvw;
  const float4* q4 = (const float4*)q;
  int wb = c * 512 + h * 16;  // float4 idx of kv_w[c][h*64]
  int qb = h * 16;
  float acc = 0.f;
#pragma unroll
  for (int i = 0; i < 16; ++i) {
    float4 w = kvw4[wb + i];
    float4 qq = q4[qb + i];
    acc += w.x * qq.x + w.y * qq.y + w.z * qq.z + w.w * qq.w;
  }
  wqk[h * 1024 + c] = acc * 0.125f;  // scale = 1/sqrt(64)
}

// ---- kernel B: logits[b][h][j] = hidden[b,j,:] . wqk[h][:] ----
// grid (16 jt, 32 b), 256 thr. Wave lane = (jr,h): 4 rows x 16 heads.
// wqk staged in LDS (64KB), rotated by h in float4 slots to spread banks.
__global__ __launch_bounds__(256) void k_logits(const float* __restrict__ hid,
                                                const float* __restrict__ wqk_g,
                                                float* __restrict__ logits) {
  __shared__ float4 lwqk[16][256];  // 65536 B
  int tid = threadIdx.x;
  int b = blockIdx.y, jt = blockIdx.x;
  const float4* wq4 = (const float4*)wqk_g;
  for (int i = tid; i < 4096; i += 256) {
    int h = i >> 8, c4 = i & 255;
    lwqk[h][(c4 + h) & 255] = wq4[i];
  }
  __syncthreads();
  int lane = tid & 63, wid = tid >> 6;
  int jr = lane >> 4, h = lane & 15;
  const float4* hid4 = (const float4*)hid;
  for (int rg = 0; rg < 8; ++rg) {
    int j = jt * 128 + rg * 16 + wid * 4 + jr;
    int base = (b * 2048 + j) * 256;
    float a0 = 0.f, a1 = 0.f, a2 = 0.f, a3 = 0.f;
    for (int c4 = 0; c4 < 256; c4 += 4) {
      float4 x0 = hid4[base + c4 + 0];
      float4 x1 = hid4[base + c4 + 1];
      float4 x2 = hid4[base + c4 + 2];
      float4 x3 = hid4[base + c4 + 3];
      float4 w0 = lwqk[h][(c4 + 0 + h) & 255];
      float4 w1 = lwqk[h][(c4 + 1 + h) & 255];
      float4 w2 = lwqk[h][(c4 + 2 + h) & 255];
      float4 w3 = lwqk[h][(c4 + 3 + h) & 255];
      a0 += x0.x * w0.x + x0.y * w0.y + x0.z * w0.z + x0.w * w0.w;
      a1 += x1.x * w1.x + x1.y * w1.y + x1.z * w1.z + x1.w * w1.w;
      a2 += x2.x * w2.x + x2.y * w2.y + x2.z * w2.z + x2.w * w2.w;
      a3 += x3.x * w3.x + x3.y * w3.y + x3.z * w3.z + x3.w * w3.w;
    }
    logits[(b * NH + h) * 2048 + j] = (a0 + a1) + (a2 + a3);
  }
}

// ---- kernel C: in-place masked softmax over j per (b,h) row ----
__global__ __launch_bounds__(256) void k_softmax(float* __restrict__ lg,
                                                 const int* __restrict__ mask) {
  int bh = blockIdx.x;  // 512
  int b = bh >> 4;
  int tid = threadIdx.x;
  __shared__ float redm[4];
  __shared__ float reds[4];
  float4* lg4 = (float4*)lg + bh * 512;
  const int4* m4 = (const int4*)mask + b * 512;
  float4 la = lg4[tid], lb = lg4[tid + 256];
  int4 ma = m4[tid], mb = m4[tid + 256];
  const float NI = -INFINITY;
  la.x = ma.x ? la.x : NI; la.y = ma.y ? la.y : NI;
  la.z = ma.z ? la.z : NI; la.w = ma.w ? la.w : NI;
  lb.x = mb.x ? lb.x : NI; lb.y = mb.y ? lb.y : NI;
  lb.z = mb.z ? lb.z : NI; lb.w = mb.w ? lb.w : NI;
  float mx = fmaxf(fmaxf(fmaxf(la.x, la.y), fmaxf(la.z, la.w)),
                   fmaxf(fmaxf(lb.x, lb.y), fmaxf(lb.z, lb.w)));
  for (int off = 32; off; off >>= 1) mx = fmaxf(mx, __shfl_xor(mx, off));
  if ((tid & 63) == 0) redm[tid >> 6] = mx;
  __syncthreads();
  mx = fmaxf(fmaxf(redm[0], redm[1]), fmaxf(redm[2], redm[3]));
  la.x = expf(la.x - mx); la.y = expf(la.y - mx);
  la.z = expf(la.z - mx); la.w = expf(la.w - mx);
  lb.x = expf(lb.x - mx); lb.y = expf(lb.y - mx);
  lb.z = expf(lb.z - mx); lb.w = expf(lb.w - mx);
  float s = la.x + la.y + la.z + la.w + lb.x + lb.y + lb.z + lb.w;
  for (int off = 32; off; off >>= 1) s += __shfl_xor(s, off);
  if ((tid & 63) == 0) reds[tid >> 6] = s;
  __syncthreads();
  s = reds[0] + reds[1] + reds[2] + reds[3];
  float inv = 1.0f / s;
  la.x *= inv; la.y *= inv; la.z *= inv; la.w *= inv;
  lb.x *= inv; lb.y *= inv; lb.z *= inv; lb.w *= inv;
  lg4[tid] = la;
  lg4[tid + 256] = lb;
}

// ---- kernel D: pooled[b][h][c] += sum_{j in chunk} w[b,h,j]*hidden[b,j,c] ----
// grid (8 ch, 32 b), 256 thr; thread owns c4 = tid*4, acc over 16 heads.
// Cross-chunk combine via global atomicAdd into pooled (memset to 0 first).
#define FMA4(A, S) { A.x = fmaf(S, x.x, A.x); A.y = fmaf(S, x.y, A.y); \
                     A.z = fmaf(S, x.z, A.z); A.w = fmaf(S, x.w, A.w); }
__global__ __launch_bounds__(256) void k_pool(const float* __restrict__ hid,
                                              const float* __restrict__ w_g,
                                              float* __restrict__ pooled) {
  __shared__ float lw[256][16];  // [jj][h], 16 KB
  int tid = threadIdx.x;
  int ch = blockIdx.x, b = blockIdx.y;
  int j0 = ch * 256;
  for (int i = tid; i < 4096; i += 256) {
    int jj = i >> 4, h = i & 15;
    lw[jj][h] = w_g[(b * NH + h) * 2048 + j0 + jj];
  }
  __syncthreads();
  float4 acc[16];
#pragma unroll
  for (int h = 0; h < 16; ++h) acc[h] = make_float4(0.f, 0.f, 0.f, 0.f);
  const float4* hid4 = (const float4*)hid + (b * 2048 + j0) * 256 + tid;
#pragma unroll 2
  for (int jj = 0; jj < 256; ++jj) {
    float4 x = hid4[jj * 256];
    float4 w0 = *(const float4*)&lw[jj][0];
    float4 w1 = *(const float4*)&lw[jj][4];
    float4 w2 = *(const float4*)&lw[jj][8];
    float4 w3 = *(const float4*)&lw[jj][12];
    FMA4(acc[0], w0.x) FMA4(acc[1], w0.y) FMA4(acc[2], w0.z) FMA4(acc[3], w0.w)
    FMA4(acc[4], w1.x) FMA4(acc[5], w1.y) FMA4(acc[6], w1.z) FMA4(acc[7], w1.w)
    FMA4(acc[8], w2.x) FMA4(acc[9], w2.y) FMA4(acc[10], w2.z) FMA4(acc[11], w2.w)
    FMA4(acc[12], w3.x) FMA4(acc[13], w3.y) FMA4(acc[14], w3.z) FMA4(acc[15], w3.w)
  }
  float* pbase = pooled + b * NH * 1024 + tid * 4;
#pragma unroll
  for (int h = 0; h < 16; ++h) {
    float* p = pbase + h * 1024;
    atomicAdd(p + 0, acc[h].x);
    atomicAdd(p + 1, acc[h].y);
    atomicAdd(p + 2, acc[h].z);
    atomicAdd(p + 3, acc[h].w);
  }
}

// ---- kernel E: project pooled through V-half of kv_w, add V-bias ----
// grid 512 = (b*16+h), 256 thr.
__global__ __launch_bounds__(256) void k_vproj(const float* __restrict__ pooled,
                                               const float* __restrict__ kvw,
                                               const float* __restrict__ kvb,
                                               float* __restrict__ out_pre) {
  int bh = blockIdx.x;
  int b = bh >> 4, h = bh & 15;
  int tid = threadIdx.x;
  __shared__ float pool[1024];
  __shared__ float red[4][64];
  const float4* p4 = (const float4*)pooled + (b * NH + h) * 256 + tid;
  *(float4*)&pool[tid * 4] = p4[0];
  __syncthreads();
  int cq = tid >> 6, lane = tid & 63;
  int coff = lane >> 4, d4 = lane & 15;
  const float4* kv4 = (const float4*)kvw;
  float4 a = make_float4(0.f, 0.f, 0.f, 0.f);
#pragma unroll 4
  for (int i = 0; i < 64; ++i) {
    int c = cq * 256 + i * 4 + coff;
    float pc = pool[c];
    float4 wv = kv4[c * 512 + 256 + h * 16 + d4];  // kv_w[c][1024+h*64+d4*4..]
    a.x = fmaf(pc, wv.x, a.x); a.y = fmaf(pc, wv.y, a.y);
    a.z = fmaf(pc, wv.z, a.z); a.w = fmaf(pc, wv.w, a.w);
  }
  a.x += __shfl_xor(a.x, 16); a.y += __shfl_xor(a.y, 16);
  a.z += __shfl_xor(a.z, 16); a.w += __shfl_xor(a.w, 16);
  a.x += __shfl_xor(a.x, 32); a.y += __shfl_xor(a.y, 32);
  a.z += __shfl_xor(a.z, 32); a.w += __shfl_xor(a.w, 32);
  if (coff == 0) *(float4*)&red[cq][d4 * 4] = a;
  __syncthreads();
  if (tid < 64) {
    float o = red[0][tid] + red[1][tid] + red[2][tid] + red[3][tid]
            + kvb[1024 + h * 64 + tid];
    out_pre[b * 1024 + h * 64 + tid] = o;
  }
}

// ---- kernel F: final = out_pre[32,1024] @ out_w[1024,1024] + out_b ----
__global__ __launch_bounds__(256) void k_final(const float* __restrict__ out_pre,
                                               const float* __restrict__ ow,
                                               const float* __restrict__ ob,
                                               float* __restrict__ out) {
  int pc = blockIdx.x, b = blockIdx.y;
  int p = pc * 256 + threadIdx.x;
  float acc = ob[p];
  const float* xp = out_pre + b * 1024;
#pragma unroll 8
  for (int k = 0; k < 1024; ++k) {
    acc = fmaf(xp[k], ow[k * 1024 + p], acc);
  }
  out[b * 1024 + p] = acc;
}

extern "C" void kernel_launch(void* const* d_in, const int* in_sizes, int n_in,
                              void* d_out, int out_size, void* d_ws, size_t ws_size,
                              hipStream_t stream) {
  const float* hid = (const float*)d_in[0];
  const int* mask = (const int*)d_in[1];
  const float* kvw = (const float*)d_in[2];
  const float* kvb = (const float*)d_in[3];
  const float* ow  = (const float*)d_in[4];
  const float* ob  = (const float*)d_in[5];
  const float* q   = (const float*)d_in[6];
  float* ws = (float*)d_ws;
  float* wqk     = ws;                       // 16384 floats
  float* logits  = ws + 16384;               // 1048576 floats
  float* pooled  = ws + 16384 + 1048576;     // 524288 floats
  float* out_pre = pooled + 524288;          // 32768 floats

  hipMemsetAsync(pooled, 0, 524288 * sizeof(float), stream);
  hipLaunchKernelGGL(k_wqk,     dim3(64),      dim3(256), 0, stream, q, kvw, wqk);
  hipLaunchKernelGGL(k_logits,  dim3(16, 32),  dim3(256), 0, stream, hid, wqk, logits);
  hipLaunchKernelGGL(k_softmax, dim3(512),     dim3(256), 0, stream, logits, mask);
  hipLaunchKernelGGL(k_pool,    dim3(8, 32),   dim3(256), 0, stream, hid, logits, pooled);
  hipLaunchKernelGGL(k_vproj,   dim3(512),     dim3(256), 0, stream, pooled, kvw, kvb, out_pre);
  hipLaunchKernelGGL(k_final,   dim3(4, 32),   dim3(256), 0, stream, out_pre, ow, ob, (float*)d_out);
}

// Round 4
// 631.204 us; speedup vs baseline: 1.1060x; 1.1060x over previous
//
#include <hip/hip_runtime.h>
#include <hip/hip_bf16.h>
#include <math.h>

// AudioAttentionPooler on MI355X.
// B=32 T=2048 HIDDEN=1024 NH=16 HD=64 PROJ=1024.
//
// Algebra: K-projection folded into a [16][1024] matrix wqk (K-bias cancels in
// softmax); V-projection deferred until after pooling hidden (attn sums to 1,
// so V-bias adds directly). Two 256MiB streaming passes over hidden_states.
//
// R4 changes (theory: latency-bound at 21% occupancy):
//  - k_logits: 512-thr blocks -> 2 blocks/CU (64KB LDS each) = 16 waves/CU.
//  - k_pool:   1024-thr blocks, wave=(head-group, c-segment), each (h,c) owned
//              by one wave; dual epilogue: deterministic part-buffer if ws fits,
//              else atomicAdd (validated R3 path).
//
// ws layout (floats):
//   wqk     [16][1024]        @ 0        (16384)
//   logits  [32][16][2048]    @ 16384    (1048576)  (overwritten with softmax w)
//   buf                       @ 1064960  (4194304 if part path else 524288)
//     part  [8ch][32b][16h][1024c]   (part path, 16.8 MB)
//     pooled[32b][16h][1024c]        (atomic path, 2 MB, memset first)
//   out_pre [32][1024]        after buf (32768)

#define NH 16

// ---- kernel A: wqk[h][c] = scale * sum_d q[h*64+d] * kv_w[c][h*64+d] ----
__global__ __launch_bounds__(256) void k_wqk(const float* __restrict__ q,
                                             const float* __restrict__ kvw,
                                             float* __restrict__ wqk) {
  int t = blockIdx.x * 256 + threadIdx.x;  // 16384 = 1024 c * 16 h
  int c = t >> 4, h = t & 15;
  const float4* kvw4 = (const float4*)kvw;
  const float4* q4 = (const float4*)q;
  int wb = c * 512 + h * 16;  // float4 idx of kv_w[c][h*64]
  int qb = h * 16;
  float acc = 0.f;
#pragma unroll
  for (int i = 0; i < 16; ++i) {
    float4 w = kvw4[wb + i];
    float4 qq = q4[qb + i];
    acc += w.x * qq.x + w.y * qq.y + w.z * qq.z + w.w * qq.w;
  }
  wqk[h * 1024 + c] = acc * 0.125f;  // scale = 1/sqrt(64)
}

// ---- kernel B: logits[b][h][j] = hidden[b,j,:] . wqk[h][:] ----
// grid (16 jt, 32 b), 512 thr (8 waves). Wave lane = (jr,h): 4 rows x 16 heads.
// wqk staged in LDS (64KB), rotated by h in float4 slots to spread banks.
// 2 blocks/CU (128KB LDS, VGPR<=128 via launch_bounds) -> 16 waves/CU.
__global__ __launch_bounds__(512, 4) void k_logits(const float* __restrict__ hid,
                                                   const float* __restrict__ wqk_g,
                                                   float* __restrict__ logits) {
  __shared__ float4 lwqk[16][256];  // 65536 B
  int tid = threadIdx.x;
  int b = blockIdx.y, jt = blockIdx.x;
  const float4* wq4 = (const float4*)wqk_g;
  for (int i = tid; i < 4096; i += 512) {
    int h = i >> 8, c4 = i & 255;
    lwqk[h][(c4 + h) & 255] = wq4[i];
  }
  __syncthreads();
  int lane = tid & 63, wid = tid >> 6;  // wid 0..7
  int jr = lane >> 4, h = lane & 15;
  const float4* hid4 = (const float4*)hid;
  for (int rg = 0; rg < 4; ++rg) {
    int j = jt * 128 + rg * 32 + wid * 4 + jr;
    int base = (b * 2048 + j) * 256;
    float a0 = 0.f, a1 = 0.f, a2 = 0.f, a3 = 0.f;
    for (int c4 = 0; c4 < 256; c4 += 4) {
      float4 x0 = hid4[base + c4 + 0];
      float4 x1 = hid4[base + c4 + 1];
      float4 x2 = hid4[base + c4 + 2];
      float4 x3 = hid4[base + c4 + 3];
      float4 w0 = lwqk[h][(c4 + 0 + h) & 255];
      float4 w1 = lwqk[h][(c4 + 1 + h) & 255];
      float4 w2 = lwqk[h][(c4 + 2 + h) & 255];
      float4 w3 = lwqk[h][(c4 + 3 + h) & 255];
      a0 += x0.x * w0.x + x0.y * w0.y + x0.z * w0.z + x0.w * w0.w;
      a1 += x1.x * w1.x + x1.y * w1.y + x1.z * w1.z + x1.w * w1.w;
      a2 += x2.x * w2.x + x2.y * w2.y + x2.z * w2.z + x2.w * w2.w;
      a3 += x3.x * w3.x + x3.y * w3.y + x3.z * w3.z + x3.w * w3.w;
    }
    logits[(b * NH + h) * 2048 + j] = (a0 + a1) + (a2 + a3);
  }
}

// ---- kernel C: in-place masked softmax over j per (b,h) row ----
__global__ __launch_bounds__(256) void k_softmax(float* __restrict__ lg,
                                                 const int* __restrict__ mask) {
  int bh = blockIdx.x;  // 512
  int b = bh >> 4;
  int tid = threadIdx.x;
  __shared__ float redm[4];
  __shared__ float reds[4];
  float4* lg4 = (float4*)lg + bh * 512;
  const int4* m4 = (const int4*)mask + b * 512;
  float4 la = lg4[tid], lb = lg4[tid + 256];
  int4 ma = m4[tid], mb = m4[tid + 256];
  const float NI = -INFINITY;
  la.x = ma.x ? la.x : NI; la.y = ma.y ? la.y : NI;
  la.z = ma.z ? la.z : NI; la.w = ma.w ? la.w : NI;
  lb.x = mb.x ? lb.x : NI; lb.y = mb.y ? lb.y : NI;
  lb.z = mb.z ? lb.z : NI; lb.w = mb.w ? lb.w : NI;
  float mx = fmaxf(fmaxf(fmaxf(la.x, la.y), fmaxf(la.z, la.w)),
                   fmaxf(fmaxf(lb.x, lb.y), fmaxf(lb.z, lb.w)));
  for (int off = 32; off; off >>= 1) mx = fmaxf(mx, __shfl_xor(mx, off));
  if ((tid & 63) == 0) redm[tid >> 6] = mx;
  __syncthreads();
  mx = fmaxf(fmaxf(redm[0], redm[1]), fmaxf(redm[2], redm[3]));
  la.x = expf(la.x - mx); la.y = expf(la.y - mx);
  la.z = expf(la.z - mx); la.w = expf(la.w - mx);
  lb.x = expf(lb.x - mx); lb.y = expf(lb.y - mx);
  lb.z = expf(lb.z - mx); lb.w = expf(lb.w - mx);
  float s = la.x + la.y + la.z + la.w + lb.x + lb.y + lb.z + lb.w;
  for (int off = 32; off; off >>= 1) s += __shfl_xor(s, off);
  if ((tid & 63) == 0) reds[tid >> 6] = s;
  __syncthreads();
  s = reds[0] + reds[1] + reds[2] + reds[3];
  float inv = 1.0f / s;
  la.x *= inv; la.y *= inv; la.z *= inv; la.w *= inv;
  lb.x *= inv; lb.y *= inv; lb.z *= inv; lb.w *= inv;
  lg4[tid] = la;
  lg4[tid + 256] = lb;
}

// ---- kernel D: pool hidden with softmax weights ----
// grid (8 ch, 32 b), 1024 thr = 16 waves. Wave = (hg 0..3, cseg 0..3):
// owns heads hg*4..hg*4+3 and float4-cols cseg*64+lane. Each (h,c) has exactly
// one owner wave -> no intra-block combine. 256 rows per chunk.
// Epilogue: part-store (use_part) or atomicAdd into pooled.
__global__ __launch_bounds__(1024, 4) void k_pool(const float* __restrict__ hid,
                                                  const float* __restrict__ w_g,
                                                  float* __restrict__ dst,
                                                  int use_part) {
  __shared__ float lw[256][16];  // [jj][h], 16 KB
  int tid = threadIdx.x;
  int ch = blockIdx.x, b = blockIdx.y;
  int j0 = ch * 256;
  for (int i = tid; i < 4096; i += 1024) {
    int jj = i >> 4, h = i & 15;
    lw[jj][h] = w_g[(b * NH + h) * 2048 + j0 + jj];
  }
  __syncthreads();
  int lane = tid & 63, wave = tid >> 6;
  int hg = wave >> 2, cseg = wave & 3;
  int h0 = hg * 4;
  int f = cseg * 64 + lane;  // float4 column 0..255
  const float4* hrow = (const float4*)hid + (b * 2048 + j0) * 256 + f;
  float4 a0 = make_float4(0.f, 0.f, 0.f, 0.f);
  float4 a1 = a0, a2 = a0, a3 = a0;
#pragma unroll 4
  for (int jj = 0; jj < 256; ++jj) {
    float4 x = hrow[jj * 256];
    float w0 = lw[jj][h0 + 0];
    float w1 = lw[jj][h0 + 1];
    float w2 = lw[jj][h0 + 2];
    float w3 = lw[jj][h0 + 3];
    a0.x = fmaf(w0, x.x, a0.x); a0.y = fmaf(w0, x.y, a0.y);
    a0.z = fmaf(w0, x.z, a0.z); a0.w = fmaf(w0, x.w, a0.w);
    a1.x = fmaf(w1, x.x, a1.x); a1.y = fmaf(w1, x.y, a1.y);
    a1.z = fmaf(w1, x.z, a1.z); a1.w = fmaf(w1, x.w, a1.w);
    a2.x = fmaf(w2, x.x, a2.x); a2.y = fmaf(w2, x.y, a2.y);
    a2.z = fmaf(w2, x.z, a2.z); a2.w = fmaf(w2, x.w, a2.w);
    a3.x = fmaf(w3, x.x, a3.x); a3.y = fmaf(w3, x.y, a3.y);
    a3.z = fmaf(w3, x.z, a3.z); a3.w = fmaf(w3, x.w, a3.w);
  }
  if (use_part) {
    // part[ch][b][h][c], float4 index: ch*131072 + (b*16+h)*256 + f
    float4* p4 = (float4*)dst + ch * 131072 + (b * NH + h0) * 256 + f;
    p4[0 * 256] = a0;
    p4[1 * 256] = a1;
    p4[2 * 256] = a2;
    p4[3 * 256] = a3;
  } else {
    float* p = dst + (b * NH + h0) * 1024 + f * 4;
    atomicAdd(p + 0,    a0.x); atomicAdd(p + 1,    a0.y);
    atomicAdd(p + 2,    a0.z); atomicAdd(p + 3,    a0.w);
    p += 1024;
    atomicAdd(p + 0,    a1.x); atomicAdd(p + 1,    a1.y);
    atomicAdd(p + 2,    a1.z); atomicAdd(p + 3,    a1.w);
    p += 1024;
    atomicAdd(p + 0,    a2.x); atomicAdd(p + 1,    a2.y);
    atomicAdd(p + 2,    a2.z); atomicAdd(p + 3,    a2.w);
    p += 1024;
    atomicAdd(p + 0,    a3.x); atomicAdd(p + 1,    a3.y);
    atomicAdd(p + 2,    a3.z); atomicAdd(p + 3,    a3.w);
  }
}

// ---- kernel E: reduce nch chunk partials + project through V-half of kv_w ----
// grid 512 = (b*16+h), 256 thr. Chunk stride = 131072 float4 (=32*16*1024 f).
__global__ __launch_bounds__(256) void k_vproj(const float* __restrict__ src,
                                               const float* __restrict__ kvw,
                                               const float* __restrict__ kvb,
                                               float* __restrict__ out_pre,
                                               int nch) {
  int bh = blockIdx.x;
  int b = bh >> 4, h = bh & 15;
  int tid = threadIdx.x;
  __shared__ float pool[1024];
  __shared__ float red[4][64];
  const float4* p4 = (const float4*)src + (b * NH + h) * 256 + tid;
  float4 s = p4[0];
  for (int ch = 1; ch < nch; ++ch) {
    float4 v = p4[ch * 131072];
    s.x += v.x; s.y += v.y; s.z += v.z; s.w += v.w;
  }
  *(float4*)&pool[tid * 4] = s;
  __syncthreads();
  int cq = tid >> 6, lane = tid & 63;
  int coff = lane >> 4, d4 = lane & 15;
  const float4* kv4 = (const float4*)kvw;
  float4 a = make_float4(0.f, 0.f, 0.f, 0.f);
#pragma unroll 4
  for (int i = 0; i < 64; ++i) {
    int c = cq * 256 + i * 4 + coff;
    float pc = pool[c];
    float4 wv = kv4[c * 512 + 256 + h * 16 + d4];  // kv_w[c][1024+h*64+d4*4..]
    a.x = fmaf(pc, wv.x, a.x); a.y = fmaf(pc, wv.y, a.y);
    a.z = fmaf(pc, wv.z, a.z); a.w = fmaf(pc, wv.w, a.w);
  }
  a.x += __shfl_xor(a.x, 16); a.y += __shfl_xor(a.y, 16);
  a.z += __shfl_xor(a.z, 16); a.w += __shfl_xor(a.w, 16);
  a.x += __shfl_xor(a.x, 32); a.y += __shfl_xor(a.y, 32);
  a.z += __shfl_xor(a.z, 32); a.w += __shfl_xor(a.w, 32);
  if (coff == 0) *(float4*)&red[cq][d4 * 4] = a;
  __syncthreads();
  if (tid < 64) {
    float o = red[0][tid] + red[1][tid] + red[2][tid] + red[3][tid]
            + kvb[1024 + h * 64 + tid];
    out_pre[b * 1024 + h * 64 + tid] = o;
  }
}

// ---- kernel F: final = out_pre[32,1024] @ out_w[1024,1024] + out_b ----
__global__ __launch_bounds__(256) void k_final(const float* __restrict__ out_pre,
                                               const float* __restrict__ ow,
                                               const float* __restrict__ ob,
                                               float* __restrict__ out) {
  int pc = blockIdx.x, b = blockIdx.y;
  int p = pc * 256 + threadIdx.x;
  float acc = ob[p];
  const float* xp = out_pre + b * 1024;
#pragma unroll 8
  for (int k = 0; k < 1024; ++k) {
    acc = fmaf(xp[k], ow[k * 1024 + p], acc);
  }
  out[b * 1024 + p] = acc;
}

extern "C" void kernel_launch(void* const* d_in, const int* in_sizes, int n_in,
                              void* d_out, int out_size, void* d_ws, size_t ws_size,
                              hipStream_t stream) {
  const float* hid = (const float*)d_in[0];
  const int* mask = (const int*)d_in[1];
  const float* kvw = (const float*)d_in[2];
  const float* kvb = (const float*)d_in[3];
  const float* ow  = (const float*)d_in[4];
  const float* ob  = (const float*)d_in[5];
  const float* q   = (const float*)d_in[6];
  float* ws = (float*)d_ws;
  float* wqk    = ws;                    // 16384 floats
  float* logits = ws + 16384;            // 1048576 floats
  float* buf    = ws + 16384 + 1048576;  // part (4194304) or pooled (524288)

  // part path needs (16384+1048576+4194304+32768)*4 = 21,168,128 B
  const int use_part = (ws_size >= (size_t)21168128) ? 1 : 0;
  float* out_pre = buf + (use_part ? 4194304 : 524288);
  const int nch = use_part ? 8 : 1;

  if (!use_part) {
    hipMemsetAsync(buf, 0, 524288 * sizeof(float), stream);
  }
  hipLaunchKernelGGL(k_wqk,     dim3(64),      dim3(256),  0, stream, q, kvw, wqk);
  hipLaunchKernelGGL(k_logits,  dim3(16, 32),  dim3(512),  0, stream, hid, wqk, logits);
  hipLaunchKernelGGL(k_softmax, dim3(512),     dim3(256),  0, stream, logits, mask);
  hipLaunchKernelGGL(k_pool,    dim3(8, 32),   dim3(1024), 0, stream, hid, logits, buf, use_part);
  hipLaunchKernelGGL(k_vproj,   dim3(512),     dim3(256),  0, stream, buf, kvw, kvb, out_pre, nch);
  hipLaunchKernelGGL(k_final,   dim3(4, 32),   dim3(256),  0, stream, out_pre, ow, ob, (float*)d_out);
}